// Round 14
// baseline (196.203 us; speedup 1.0000x reference)
//
#include <hip/hip_runtime.h>
#include <hip/hip_bf16.h>
#include <cstdint>
#include <cstddef>

// Problem constants
constexpr int B_ = 2, T_ = 4096, C_ = 768, H_ = 12, HD_ = 64;
constexpr int M_ = B_ * T_;      // 8192 rows of x
constexpr int NQKV_ = 3 * C_;    // 2304

typedef __bf16 bf16_t;
typedef __bf16 bf16x8 __attribute__((ext_vector_type(8)));
typedef __bf16 bf16x4 __attribute__((ext_vector_type(4)));
typedef __bf16 bf16x2 __attribute__((ext_vector_type(2)));
typedef float  f32x4  __attribute__((ext_vector_type(4)));
typedef float  f32x16 __attribute__((ext_vector_type(16)));
typedef unsigned int u32;
typedef unsigned int u32x4 __attribute__((ext_vector_type(4)));

typedef const __attribute__((address_space(1))) void* gas_t;
typedef __attribute__((address_space(3))) void* las_t;

// Q pre-scale: 1/sqrt(64) * log2(e)  (softmax done in exp2 domain).
// Folded into W_attn's Q rows during conversion.
#define QSCALE 0.1803368801111204f

static __device__ __forceinline__ u32 pkbf16(float a, float b) {
  bf16x2 t;
  t[0] = (bf16_t)a;
  t[1] = (bf16_t)b;
  return __builtin_bit_cast(u32, t);
}

// ---------------------------------------------------------------------------
// Merged f32 -> bf16 conversion for x, w_attn, w_proj in ONE launch.
// w_attn rows [0,768) (the Q rows) are pre-scaled by QSCALE.
// ---------------------------------------------------------------------------
constexpr int N4_X  = M_ * C_ / 4;          // 1572864
constexpr int N4_WA = NQKV_ * C_ / 4;       // 442368
constexpr int N4_WP = C_ * C_ / 4;          // 147456
constexpr int N4_QROWS = C_ * C_ / 4;       // wa's first 768 rows in f4 units

__global__ void cvt_all(const float* __restrict__ x,
                        const float* __restrict__ wa,
                        const float* __restrict__ wp,
                        bf16_t* __restrict__ xb,
                        bf16_t* __restrict__ wab,
                        bf16_t* __restrict__ wpb) {
  int i = blockIdx.x * blockDim.x + threadIdx.x;
  const int st = gridDim.x * blockDim.x;
  const int n4 = N4_X + N4_WA + N4_WP;
  for (; i < n4; i += st) {
    const float* s;
    bf16_t* d;
    int k;
    float sc = 1.0f;
    if (i < N4_X) {
      s = x; d = xb; k = i;
    } else if (i < N4_X + N4_WA) {
      s = wa; d = wab; k = i - N4_X;
      if (k < N4_QROWS) sc = QSCALE;
    } else {
      s = wp; d = wpb; k = i - N4_X - N4_WA;
    }
    const float4 v = reinterpret_cast<const float4*>(s)[k];
    bf16x4 o;
    o[0] = (bf16_t)(v.x * sc); o[1] = (bf16_t)(v.y * sc);
    o[2] = (bf16_t)(v.z * sc); o[3] = (bf16_t)(v.w * sc);
    reinterpret_cast<bf16x4*>(d)[k] = o;
  }
}

// ===========================================================================
// Staged GEMM core (m97 structure): 128x128 tile, BK=32, dbuf LDS 32 KB,
// global_load_lds width=16, pre-swizzled source (chunk ^= row&3).
// ===========================================================================
#define GEMM_CORE(Xb, Wb)                                                     \
  __shared__ __align__(16) char lds[32768];                                   \
  const int tid = threadIdx.x, lane = tid & 63, wave = tid >> 6;              \
  const int r16 = lane & 15, g = lane >> 4;                                   \
  const int wr = wave >> 1, wc = wave & 1;                                    \
  const int m0 = blockIdx.y * 128;                                            \
  const int n0 = blockIdx.x * 128;                                            \
  int prow[2], goff[2];                                                       \
  _Pragma("unroll")                                                           \
  for (int i = 0; i < 2; ++i) {                                               \
    const int p = (wave * 2 + i) * 64 + lane;                                 \
    prow[i] = p >> 2;                                                         \
    goff[i] = ((p & 3) ^ (prow[i] & 3)) * 8;                                  \
  }                                                                           \
  auto stage = [&](int buf, int k0) {                                         \
    char* const base = lds + buf * 16384;                                     \
    _Pragma("unroll")                                                         \
    for (int i = 0; i < 2; ++i) {                                             \
      __builtin_amdgcn_global_load_lds(                                       \
          (gas_t)(Xb + (size_t)prow[i] * C_ + k0 + goff[i]),                  \
          (las_t)(base + (wave * 2 + i) * 1024), 16, 0, 0);                   \
      __builtin_amdgcn_global_load_lds(                                       \
          (gas_t)(Wb + (size_t)prow[i] * C_ + k0 + goff[i]),                  \
          (las_t)(base + 8192 + (wave * 2 + i) * 1024), 16, 0, 0);            \
    }                                                                         \
  };                                                                          \
  f32x4 acc[4][4] = {};                                                       \
  const int kswz = (g ^ (r16 & 3)) * 16;                                      \
  stage(0, 0);                                                                \
  __syncthreads();                                                            \
  constexpr int KT = C_ / 32;                                                 \
  for (int kt = 0; kt < KT; ++kt) {                                           \
    if (kt + 1 < KT) stage((kt + 1) & 1, (kt + 1) * 32);                      \
    const char* Ab = lds + (kt & 1) * 16384;                                  \
    const char* Bb = Ab + 8192;                                               \
    bf16x8 a[4], b[4];                                                        \
    _Pragma("unroll")                                                         \
    for (int i = 0; i < 4; ++i)                                               \
      a[i] = *reinterpret_cast<const bf16x8*>(                                \
          Ab + (wr * 64 + i * 16 + r16) * 64 + kswz);                         \
    _Pragma("unroll")                                                         \
    for (int j = 0; j < 4; ++j)                                               \
      b[j] = *reinterpret_cast<const bf16x8*>(                                \
          Bb + (wc * 64 + j * 16 + r16) * 64 + kswz);                         \
    _Pragma("unroll")                                                         \
    for (int i = 0; i < 4; ++i)                                               \
      _Pragma("unroll")                                                       \
      for (int j = 0; j < 4; ++j)                                             \
        acc[i][j] = __builtin_amdgcn_mfma_f32_16x16x32_bf16(                  \
            a[i], b[j], acc[i][j], 0, 0, 0);                                  \
    __syncthreads();                                                          \
  }

// ---------------------------------------------------------------------------
// QKV projection -> Q,K ([B,H,T,64]) and V transposed ([B,H,64,T]).
// QSCALE is pre-folded into W_attn's Q rows.  V packs 4 consecutive-t
// values into one bf16x4 store.
// ---------------------------------------------------------------------------
__global__ __launch_bounds__(256) void gemm_qkv(
    const bf16_t* __restrict__ X, const bf16_t* __restrict__ W,
    bf16_t* __restrict__ Q, bf16_t* __restrict__ K, bf16_t* __restrict__ Vt) {
  GEMM_CORE(X + (size_t)blockIdx.y * 128 * C_,
            W + (size_t)blockIdx.x * 128 * C_)

#pragma unroll
  for (int j = 0; j < 4; ++j) {
    const int col = n0 + wc * 64 + j * 16 + r16;
    const int which = col / C_;           // 0=Q, 1=K, 2=V (wave-uniform)
    const int c = col - which * C_;
    const int h = c >> 6, d = c & 63;
#pragma unroll
    for (int i = 0; i < 4; ++i) {
      const int row0 = m0 + wr * 64 + i * 16 + g * 4;   // quad-aligned
      const int bb = row0 >> 12, t0 = row0 & (T_ - 1);
      if (which == 2) {
        bf16x4 pv;
#pragma unroll
        for (int r = 0; r < 4; ++r) pv[r] = (bf16_t)acc[i][j][r];
        *reinterpret_cast<bf16x4*>(
            &Vt[(((size_t)(bb * H_ + h)) * HD_ + d) * (size_t)T_ + t0]) = pv;
      } else {
        bf16_t* const dst = (which == 0) ? Q : K;
#pragma unroll
        for (int r = 0; r < 4; ++r)
          dst[(((size_t)(bb * H_ + h)) * T_ + t0 + r) * HD_ + d] =
              (bf16_t)acc[i][j][r];
      }
    }
  }
}

// ---------------------------------------------------------------------------
// Output projection: A[8192][768] * Wp[768][768]^T -> f32 out
// ---------------------------------------------------------------------------
__global__ __launch_bounds__(256) void gemm_proj(
    const bf16_t* __restrict__ A, const bf16_t* __restrict__ W,
    float* __restrict__ Out) {
  GEMM_CORE(A + (size_t)blockIdx.y * 128 * C_,
            W + (size_t)blockIdx.x * 128 * C_)

#pragma unroll
  for (int j = 0; j < 4; ++j) {
    const int col = n0 + wc * 64 + j * 16 + r16;
#pragma unroll
    for (int i = 0; i < 4; ++i)
#pragma unroll
      for (int r = 0; r < 4; ++r) {
        const int row = m0 + wr * 64 + i * 16 + g * 4 + r;
        Out[(size_t)row * C_ + col] = acc[i][j][r];
      }
  }
}

// ---------------------------------------------------------------------------
// Causal flash attention v9 body + PI-BALANCED q-tile assignment.
// CU(b)=CU(b+256) => each CU hosts blocks with j in {a, a+10/11, a+21/22}.
// v9's y=31-j gave CU work 62-3a (2x spread -> ragged drain, 36% occupancy).
// pi below makes triple sums ~[42,52] (was [32,62]): max CU work -15%.
//   j in [0,9]  -> 31-j   (heavy)
//   j = 10      -> 0
//   j in [11,20]-> j-10   (light)
//   j = 21      -> 16
//   j in [22,31]-> {11,12,13,14,15,17,18,19,20,21} ascending
// Everything inside the kernel is v9 verbatim.
// ---------------------------------------------------------------------------
__global__ __launch_bounds__(512) void attn_fwd(
    const bf16_t* __restrict__ Q, const bf16_t* __restrict__ K,
    const bf16_t* __restrict__ Vt, bf16_t* __restrict__ O) {
  __shared__ __align__(16) char lds[33280];
  const int tid = threadIdx.x;
  const int lane = tid & 63, wave = tid >> 6;    // wave 0..7
  const int wq = wave & 3;                       // q-group
  const int ksw = wave >> 2;                     // subtile parity
  const int c32 = lane & 31, h = lane >> 5;
  const int bh = blockIdx.x;
  const int j = blockIdx.y;
  int y;
  if (j < 10) y = 31 - j;
  else if (j == 10) y = 0;
  else if (j <= 20) y = j - 10;
  else if (j == 21) y = 16;
  else { const int k = j - 22; y = (k < 5) ? (11 + k) : (12 + k); }
  const int q0w = 128 * y + 32 * wq;

  const bf16_t* Qb = Q + (size_t)bh * T_ * HD_;
  const bf16_t* Kb = K + (size_t)bh * T_ * HD_;
  const bf16_t* Vb = Vt + (size_t)bh * HD_ * T_;

  // Q fragments (B operand): col=query=c32, k = dg*16 + h*8 + j
  bf16x8 qf[4];
#pragma unroll
  for (int dg = 0; dg < 4; ++dg)
    qf[dg] = *reinterpret_cast<const bf16x8*>(
        Qb + (size_t)(q0w + c32) * HD_ + dg * 16 + h * 8);

  // all-ones B fragment for the MFMA row-sum
  bf16x8 ones;
#pragma unroll
  for (int q = 0; q < 8; ++q) ones[q] = (bf16_t)1.0f;

  f32x16 o0 = {}, o1 = {};   // d 0..31 / 32..63 for 16 queries (reg=query)
  f32x16 lac = {};           // row sums, same layout as o

  // staging: 512 threads x 2 x 16B (one K chunk, one V chunk) = 16 KB tile.
  // LDS dest linear (pos = tid*16); source chunk pre-swizzled by row&7.
  const int srow = tid >> 3;
  const int sck = (tid & 7) ^ (srow & 7);

  auto STAGE = [&](int t, int buf) {
    char* const kb = lds + buf * 16384;
    __builtin_amdgcn_global_load_lds(
        (gas_t)(Kb + (size_t)(t * 64 + srow) * HD_ + sck * 8),
        (las_t)(kb + wave * 1024), 16, 0, 0);
    __builtin_amdgcn_global_load_lds(
        (gas_t)(Vb + (size_t)srow * T_ + t * 64 + sck * 8),
        (las_t)(kb + 8192 + wave * 1024), 16, 0, 0);
  };

  const int nt = 2 * y + 2;
  STAGE(0, 0);
  __syncthreads();

  for (int t = 0; t < nt; ++t) {
    if (t + 1 < nt) STAGE(t + 1, (t + 1) & 1);
    const char* kl = lds + (t & 1) * 16384;
    const char* vl = kl + 8192;
    const int kb0 = t * 64 + ksw * 32;
    if (kb0 < q0w + 32) {
      // ---- S^T = K Q^T over 32 keys (lane owns query c32) ----
      f32x16 s = {};
#pragma unroll
      for (int dg = 0; dg < 4; ++dg) {
        const bf16x8 kf = *reinterpret_cast<const bf16x8*>(
            kl + (ksw * 32 + c32) * 128 + (((dg * 2 + h) ^ (c32 & 7)) << 4));
        s = __builtin_amdgcn_mfma_f32_32x32x16_bf16(kf, qf[dg], s, 0, 0, 0);
      }
      // ---- causal mask (diagonal-crossing subtiles only) ----
      if (kb0 + 31 > q0w) {
        const int qabs = q0w + c32;
        const int kbh = kb0 + 4 * h;
#pragma unroll
        for (int r = 0; r < 16; ++r) {
          if (kbh + (r & 3) + 8 * (r >> 2) > qabs) s[r] = -130.f;
        }
      }
      // ---- P = exp2(s), fixed shift ----
#pragma unroll
      for (int r = 0; r < 16; ++r) s[r] = exp2f(s[r]);
      // ---- P -> PV A-fragments, fully in-register ----
      u32 X0 = pkbf16(s[0], s[1]),  X1 = pkbf16(s[2], s[3]);
      u32 X2 = pkbf16(s[4], s[5]),  X3 = pkbf16(s[6], s[7]);
      u32 X4 = pkbf16(s[8], s[9]),  X5 = pkbf16(s[10], s[11]);
      u32 X6 = pkbf16(s[12], s[13]), X7 = pkbf16(s[14], s[15]);
      const auto a0 = __builtin_amdgcn_permlane32_swap(X0, X2, false, false);
      const auto a1 = __builtin_amdgcn_permlane32_swap(X1, X3, false, false);
      const auto a2 = __builtin_amdgcn_permlane32_swap(X4, X6, false, false);
      const auto a3 = __builtin_amdgcn_permlane32_swap(X5, X7, false, false);
      const u32x4 w1 = {(u32)a0[0], (u32)a1[0], (u32)a0[1], (u32)a1[1]};
      const u32x4 w2 = {(u32)a2[0], (u32)a3[0], (u32)a2[1], (u32)a3[1]};
      const bf16x8 pa1 = __builtin_bit_cast(bf16x8, w1);  // keys +0..15
      const bf16x8 pa2 = __builtin_bit_cast(bf16x8, w2);  // keys +16..31
      // ---- l += P . 1  (row sums via MFMA; lands in o's layout) ----
      lac = __builtin_amdgcn_mfma_f32_32x32x16_bf16(pa1, ones, lac, 0, 0, 0);
      lac = __builtin_amdgcn_mfma_f32_32x32x16_bf16(pa2, ones, lac, 0, 0, 0);
      // ---- O += P V  (V^T tile rows = d, contiguous keys) ----
#pragma unroll
      for (int dgb = 0; dgb < 2; ++dgb) {
        const int vrow = dgb * 32 + c32;
        const bf16x8 vf0 = *reinterpret_cast<const bf16x8*>(
            vl + vrow * 128 + (((ksw * 4 + h) ^ (c32 & 7)) << 4));
        const bf16x8 vf1 = *reinterpret_cast<const bf16x8*>(
            vl + vrow * 128 + (((ksw * 4 + 2 + h) ^ (c32 & 7)) << 4));
        if (dgb == 0) {
          o0 = __builtin_amdgcn_mfma_f32_32x32x16_bf16(pa1, vf0, o0, 0, 0, 0);
          o0 = __builtin_amdgcn_mfma_f32_32x32x16_bf16(pa2, vf1, o0, 0, 0, 0);
        } else {
          o1 = __builtin_amdgcn_mfma_f32_32x32x16_bf16(pa1, vf0, o1, 0, 0, 0);
          o1 = __builtin_amdgcn_mfma_f32_32x32x16_bf16(pa2, vf1, o1, 0, 0, 0);
        }
      }
    }
    __syncthreads();
  }

  // ---- combine: odd-parity waves dump partials into the dead staging LDS --
  float* const obuf = reinterpret_cast<float*>(lds);           // 4 x 8 KB
  float* const lbuf = reinterpret_cast<float*>(lds + 32768);   // 4 x 32 f32
  if (wave >= 4) {
    float* const ob = obuf + (wave - 4) * 2048;   // [q 0..31][d 0..63]
#pragma unroll
    for (int r = 0; r < 16; ++r) {
      const int qr = (r & 3) + 8 * (r >> 2) + 4 * h;
      ob[qr * 64 + c32] = o0[r];
      ob[qr * 64 + 32 + c32] = o1[r];
      if (c32 == 0) lbuf[(wave - 4) * 32 + qr] = lac[r];
    }
  }
  __syncthreads();
  if (wave < 4) {
    const float* const ob = obuf + wave * 2048;
    const float* const lb = lbuf + wave * 32;
    const int b = bh / H_, hh = bh - b * H_;
#pragma unroll
    for (int r = 0; r < 16; ++r) {
      const int qr = (r & 3) + 8 * (r >> 2) + 4 * h;
      const float lt = 1.0f / (lac[r] + lb[qr]);
      const float v0 = o0[r] + ob[qr * 64 + c32];
      const float v1 = o1[r] + ob[qr * 64 + 32 + c32];
      const size_t rowoff = ((size_t)(b * T_ + q0w + qr)) * C_ + hh * HD_;
      O[rowoff + c32] = (bf16_t)(v0 * lt);
      O[rowoff + 32 + c32] = (bf16_t)(v1 * lt);
    }
  }
}

// ---------------------------------------------------------------------------
extern "C" void kernel_launch(void* const* d_in, const int* in_sizes, int n_in,
                              void* d_out, int out_size, void* d_ws,
                              size_t ws_size, hipStream_t stream) {
  const float* x  = (const float*)d_in[0];   // [2,4096,768]
  const float* wa = (const float*)d_in[1];   // [2304,768]
  const float* wp = (const float*)d_in[2];   // [768,768]
  float* out = (float*)d_out;                // [2,4096,768] f32

  char* ws = (char*)d_ws;
  size_t off = 0;
  auto alloc = [&](size_t bytes) -> char* {
    char* p = ws + off;
    off += (bytes + 255) & ~(size_t)255;
    return p;
  };
  bf16_t* xb  = (bf16_t*)alloc((size_t)M_ * C_ * 2);
  bf16_t* wab = (bf16_t*)alloc((size_t)NQKV_ * C_ * 2);
  bf16_t* wpb = (bf16_t*)alloc((size_t)C_ * C_ * 2);
  bf16_t* Qb  = (bf16_t*)alloc((size_t)B_ * H_ * T_ * HD_ * 2);
  bf16_t* Kb  = (bf16_t*)alloc((size_t)B_ * H_ * T_ * HD_ * 2);
  bf16_t* Vtb = (bf16_t*)alloc((size_t)B_ * H_ * HD_ * T_ * 2);
  bf16_t* Ob  = (bf16_t*)alloc((size_t)M_ * C_ * 2);
  if (off > ws_size) return;

  cvt_all<<<1024, 256, 0, stream>>>(x, wa, wp, xb, wab, wpb);

  gemm_qkv<<<dim3(NQKV_ / 128, M_ / 128), 256, 0, stream>>>(xb, wab, Qb, Kb, Vtb);
  attn_fwd<<<dim3(B_ * H_, 32), 512, 0, stream>>>(Qb, Kb, Vtb, Ob);
  gemm_proj<<<dim3(C_ / 128, M_ / 128), 256, 0, stream>>>(Ob, wpb, out);
}

// Round 15
// 169.779 us; speedup vs baseline: 1.1556x; 1.1556x over previous
//
#include <hip/hip_runtime.h>
#include <hip/hip_bf16.h>
#include <cstdint>
#include <cstddef>

// Problem constants
constexpr int B_ = 2, T_ = 4096, C_ = 768, H_ = 12, HD_ = 64;
constexpr int M_ = B_ * T_;      // 8192 rows of x
constexpr int NQKV_ = 3 * C_;    // 2304

typedef __bf16 bf16_t;
typedef __bf16 bf16x8 __attribute__((ext_vector_type(8)));
typedef __bf16 bf16x4 __attribute__((ext_vector_type(4)));
typedef __bf16 bf16x2 __attribute__((ext_vector_type(2)));
typedef float  f32x4  __attribute__((ext_vector_type(4)));
typedef float  f32x16 __attribute__((ext_vector_type(16)));
typedef unsigned int u32;
typedef unsigned int u32x4 __attribute__((ext_vector_type(4)));

typedef const __attribute__((address_space(1))) void* gas_t;
typedef __attribute__((address_space(3))) void* las_t;

// Q pre-scale: 1/sqrt(64) * log2(e)  (softmax done in exp2 domain).
// Folded into W_attn's Q rows during conversion.
#define QSCALE 0.1803368801111204f

static __device__ __forceinline__ u32 pkbf16(float a, float b) {
  bf16x2 t;
  t[0] = (bf16_t)a;
  t[1] = (bf16_t)b;
  return __builtin_bit_cast(u32, t);
}

// ---------------------------------------------------------------------------
// Merged f32 -> bf16 conversion for x, w_attn, w_proj in ONE launch.
// w_attn rows [0,768) (the Q rows) are pre-scaled by QSCALE.
// ---------------------------------------------------------------------------
constexpr int N4_X  = M_ * C_ / 4;          // 1572864
constexpr int N4_WA = NQKV_ * C_ / 4;       // 442368
constexpr int N4_WP = C_ * C_ / 4;          // 147456
constexpr int N4_QROWS = C_ * C_ / 4;       // wa's first 768 rows in f4 units

__global__ void cvt_all(const float* __restrict__ x,
                        const float* __restrict__ wa,
                        const float* __restrict__ wp,
                        bf16_t* __restrict__ xb,
                        bf16_t* __restrict__ wab,
                        bf16_t* __restrict__ wpb) {
  int i = blockIdx.x * blockDim.x + threadIdx.x;
  const int st = gridDim.x * blockDim.x;
  const int n4 = N4_X + N4_WA + N4_WP;
  for (; i < n4; i += st) {
    const float* s;
    bf16_t* d;
    int k;
    float sc = 1.0f;
    if (i < N4_X) {
      s = x; d = xb; k = i;
    } else if (i < N4_X + N4_WA) {
      s = wa; d = wab; k = i - N4_X;
      if (k < N4_QROWS) sc = QSCALE;
    } else {
      s = wp; d = wpb; k = i - N4_X - N4_WA;
    }
    const float4 v = reinterpret_cast<const float4*>(s)[k];
    bf16x4 o;
    o[0] = (bf16_t)(v.x * sc); o[1] = (bf16_t)(v.y * sc);
    o[2] = (bf16_t)(v.z * sc); o[3] = (bf16_t)(v.w * sc);
    reinterpret_cast<bf16x4*>(d)[k] = o;
  }
}

// ===========================================================================
// Staged GEMM core (m97 structure): 128x128 tile, BK=32, dbuf LDS 32 KB,
// global_load_lds width=16, pre-swizzled source (chunk ^= row&3).
// ===========================================================================
#define GEMM_CORE(Xb, Wb)                                                     \
  __shared__ __align__(16) char lds[32768];                                   \
  const int tid = threadIdx.x, lane = tid & 63, wave = tid >> 6;              \
  const int r16 = lane & 15, g = lane >> 4;                                   \
  const int wr = wave >> 1, wc = wave & 1;                                    \
  const int m0 = blockIdx.y * 128;                                            \
  const int n0 = blockIdx.x * 128;                                            \
  int prow[2], goff[2];                                                       \
  _Pragma("unroll")                                                           \
  for (int i = 0; i < 2; ++i) {                                               \
    const int p = (wave * 2 + i) * 64 + lane;                                 \
    prow[i] = p >> 2;                                                         \
    goff[i] = ((p & 3) ^ (prow[i] & 3)) * 8;                                  \
  }                                                                           \
  auto stage = [&](int buf, int k0) {                                         \
    char* const base = lds + buf * 16384;                                     \
    _Pragma("unroll")                                                         \
    for (int i = 0; i < 2; ++i) {                                             \
      __builtin_amdgcn_global_load_lds(                                       \
          (gas_t)(Xb + (size_t)prow[i] * C_ + k0 + goff[i]),                  \
          (las_t)(base + (wave * 2 + i) * 1024), 16, 0, 0);                   \
      __builtin_amdgcn_global_load_lds(                                       \
          (gas_t)(Wb + (size_t)prow[i] * C_ + k0 + goff[i]),                  \
          (las_t)(base + 8192 + (wave * 2 + i) * 1024), 16, 0, 0);            \
    }                                                                         \
  };                                                                          \
  f32x4 acc[4][4] = {};                                                       \
  const int kswz = (g ^ (r16 & 3)) * 16;                                      \
  stage(0, 0);                                                                \
  __syncthreads();                                                            \
  constexpr int KT = C_ / 32;                                                 \
  for (int kt = 0; kt < KT; ++kt) {                                           \
    if (kt + 1 < KT) stage((kt + 1) & 1, (kt + 1) * 32);                      \
    const char* Ab = lds + (kt & 1) * 16384;                                  \
    const char* Bb = Ab + 8192;                                               \
    bf16x8 a[4], b[4];                                                        \
    _Pragma("unroll")                                                         \
    for (int i = 0; i < 4; ++i)                                               \
      a[i] = *reinterpret_cast<const bf16x8*>(                                \
          Ab + (wr * 64 + i * 16 + r16) * 64 + kswz);                         \
    _Pragma("unroll")                                                         \
    for (int j = 0; j < 4; ++j)                                               \
      b[j] = *reinterpret_cast<const bf16x8*>(                                \
          Bb + (wc * 64 + j * 16 + r16) * 64 + kswz);                         \
    _Pragma("unroll")                                                         \
    for (int i = 0; i < 4; ++i)                                               \
      _Pragma("unroll")                                                       \
      for (int j = 0; j < 4; ++j)                                             \
        acc[i][j] = __builtin_amdgcn_mfma_f32_16x16x32_bf16(                  \
            a[i], b[j], acc[i][j], 0, 0, 0);                                  \
    __syncthreads();                                                          \
  }

// ---------------------------------------------------------------------------
// QKV projection -> Q,K ([B,H,T,64]) and V transposed ([B,H,64,T]).
// QSCALE is pre-folded into W_attn's Q rows.  V packs 4 consecutive-t
// values into one bf16x4 store.
// ---------------------------------------------------------------------------
__global__ __launch_bounds__(256) void gemm_qkv(
    const bf16_t* __restrict__ X, const bf16_t* __restrict__ W,
    bf16_t* __restrict__ Q, bf16_t* __restrict__ K, bf16_t* __restrict__ Vt) {
  GEMM_CORE(X + (size_t)blockIdx.y * 128 * C_,
            W + (size_t)blockIdx.x * 128 * C_)

#pragma unroll
  for (int j = 0; j < 4; ++j) {
    const int col = n0 + wc * 64 + j * 16 + r16;
    const int which = col / C_;           // 0=Q, 1=K, 2=V (wave-uniform)
    const int c = col - which * C_;
    const int h = c >> 6, d = c & 63;
#pragma unroll
    for (int i = 0; i < 4; ++i) {
      const int row0 = m0 + wr * 64 + i * 16 + g * 4;   // quad-aligned
      const int bb = row0 >> 12, t0 = row0 & (T_ - 1);
      if (which == 2) {
        bf16x4 pv;
#pragma unroll
        for (int r = 0; r < 4; ++r) pv[r] = (bf16_t)acc[i][j][r];
        *reinterpret_cast<bf16x4*>(
            &Vt[(((size_t)(bb * H_ + h)) * HD_ + d) * (size_t)T_ + t0]) = pv;
      } else {
        bf16_t* const dst = (which == 0) ? Q : K;
#pragma unroll
        for (int r = 0; r < 4; ++r)
          dst[(((size_t)(bb * H_ + h)) * T_ + t0 + r) * HD_ + d] =
              (bf16_t)acc[i][j][r];
      }
    }
  }
}

// ---------------------------------------------------------------------------
// Output projection: A[8192][768] * Wp[768][768]^T -> f32 out
// ---------------------------------------------------------------------------
__global__ __launch_bounds__(256) void gemm_proj(
    const bf16_t* __restrict__ A, const bf16_t* __restrict__ W,
    float* __restrict__ Out) {
  GEMM_CORE(A + (size_t)blockIdx.y * 128 * C_,
            W + (size_t)blockIdx.x * 128 * C_)

#pragma unroll
  for (int j = 0; j < 4; ++j) {
    const int col = n0 + wc * 64 + j * 16 + r16;
#pragma unroll
    for (int i = 0; i < 4; ++i)
#pragma unroll
      for (int r = 0; r < 4; ++r) {
        const int row = m0 + wr * 64 + i * 16 + g * 4 + r;
        Out[(size_t)row * C_ + col] = acc[i][j][r];
      }
  }
}

// ---------------------------------------------------------------------------
// Causal flash attention v9 (VERBATIM round-9/13 99us kernel; pi-map of
// round 14 reverted -- it regressed 98.6 -> 126 us by breaking the
// heavy-first drain).
// 512 threads = 8 waves.  Waves 0-3: q-groups 0-3 (32q each, 128q block),
// EVEN 32-key subtiles.  Waves 4-7: same q-groups, ODD subtiles.  Fixed-shift
// softmax => partials combine by plain addition through dead staging LDS.
// Grid: (B*H = 24 fastest -> XCD L2 locality, 32), heavy tiles first.
// ---------------------------------------------------------------------------
__global__ __launch_bounds__(512) void attn_fwd(
    const bf16_t* __restrict__ Q, const bf16_t* __restrict__ K,
    const bf16_t* __restrict__ Vt, bf16_t* __restrict__ O) {
  __shared__ __align__(16) char lds[33280];
  const int tid = threadIdx.x;
  const int lane = tid & 63, wave = tid >> 6;    // wave 0..7
  const int wq = wave & 3;                       // q-group
  const int ksw = wave >> 2;                     // subtile parity
  const int c32 = lane & 31, h = lane >> 5;
  const int bh = blockIdx.x;
  const int y = gridDim.y - 1 - blockIdx.y;      // heavy tiles first
  const int q0w = 128 * y + 32 * wq;

  const bf16_t* Qb = Q + (size_t)bh * T_ * HD_;
  const bf16_t* Kb = K + (size_t)bh * T_ * HD_;
  const bf16_t* Vb = Vt + (size_t)bh * HD_ * T_;

  // Q fragments (B operand): col=query=c32, k = dg*16 + h*8 + j
  bf16x8 qf[4];
#pragma unroll
  for (int dg = 0; dg < 4; ++dg)
    qf[dg] = *reinterpret_cast<const bf16x8*>(
        Qb + (size_t)(q0w + c32) * HD_ + dg * 16 + h * 8);

  // all-ones B fragment for the MFMA row-sum
  bf16x8 ones;
#pragma unroll
  for (int q = 0; q < 8; ++q) ones[q] = (bf16_t)1.0f;

  f32x16 o0 = {}, o1 = {};   // d 0..31 / 32..63 for 16 queries (reg=query)
  f32x16 lac = {};           // row sums, same layout as o

  // staging: 512 threads x 2 x 16B (one K chunk, one V chunk) = 16 KB tile.
  // LDS dest linear (pos = tid*16); source chunk pre-swizzled by row&7.
  const int srow = tid >> 3;
  const int sck = (tid & 7) ^ (srow & 7);

  auto STAGE = [&](int t, int buf) {
    char* const kb = lds + buf * 16384;
    __builtin_amdgcn_global_load_lds(
        (gas_t)(Kb + (size_t)(t * 64 + srow) * HD_ + sck * 8),
        (las_t)(kb + wave * 1024), 16, 0, 0);
    __builtin_amdgcn_global_load_lds(
        (gas_t)(Vb + (size_t)srow * T_ + t * 64 + sck * 8),
        (las_t)(kb + 8192 + wave * 1024), 16, 0, 0);
  };

  const int nt = 2 * y + 2;
  STAGE(0, 0);
  __syncthreads();

  for (int t = 0; t < nt; ++t) {
    if (t + 1 < nt) STAGE(t + 1, (t + 1) & 1);
    const char* kl = lds + (t & 1) * 16384;
    const char* vl = kl + 8192;
    const int kb0 = t * 64 + ksw * 32;
    if (kb0 < q0w + 32) {
      // ---- S^T = K Q^T over 32 keys (lane owns query c32) ----
      f32x16 s = {};
#pragma unroll
      for (int dg = 0; dg < 4; ++dg) {
        const bf16x8 kf = *reinterpret_cast<const bf16x8*>(
            kl + (ksw * 32 + c32) * 128 + (((dg * 2 + h) ^ (c32 & 7)) << 4));
        s = __builtin_amdgcn_mfma_f32_32x32x16_bf16(kf, qf[dg], s, 0, 0, 0);
      }
      // ---- causal mask (diagonal-crossing subtiles only) ----
      if (kb0 + 31 > q0w) {
        const int qabs = q0w + c32;
        const int kbh = kb0 + 4 * h;
#pragma unroll
        for (int r = 0; r < 16; ++r) {
          if (kbh + (r & 3) + 8 * (r >> 2) > qabs) s[r] = -130.f;
        }
      }
      // ---- P = exp2(s), fixed shift ----
#pragma unroll
      for (int r = 0; r < 16; ++r) s[r] = exp2f(s[r]);
      // ---- P -> PV A-fragments, fully in-register ----
      u32 X0 = pkbf16(s[0], s[1]),  X1 = pkbf16(s[2], s[3]);
      u32 X2 = pkbf16(s[4], s[5]),  X3 = pkbf16(s[6], s[7]);
      u32 X4 = pkbf16(s[8], s[9]),  X5 = pkbf16(s[10], s[11]);
      u32 X6 = pkbf16(s[12], s[13]), X7 = pkbf16(s[14], s[15]);
      const auto a0 = __builtin_amdgcn_permlane32_swap(X0, X2, false, false);
      const auto a1 = __builtin_amdgcn_permlane32_swap(X1, X3, false, false);
      const auto a2 = __builtin_amdgcn_permlane32_swap(X4, X6, false, false);
      const auto a3 = __builtin_amdgcn_permlane32_swap(X5, X7, false, false);
      const u32x4 w1 = {(u32)a0[0], (u32)a1[0], (u32)a0[1], (u32)a1[1]};
      const u32x4 w2 = {(u32)a2[0], (u32)a3[0], (u32)a2[1], (u32)a3[1]};
      const bf16x8 pa1 = __builtin_bit_cast(bf16x8, w1);  // keys +0..15
      const bf16x8 pa2 = __builtin_bit_cast(bf16x8, w2);  // keys +16..31
      // ---- l += P . 1  (row sums via MFMA; lands in o's layout) ----
      lac = __builtin_amdgcn_mfma_f32_32x32x16_bf16(pa1, ones, lac, 0, 0, 0);
      lac = __builtin_amdgcn_mfma_f32_32x32x16_bf16(pa2, ones, lac, 0, 0, 0);
      // ---- O += P V  (V^T tile rows = d, contiguous keys) ----
#pragma unroll
      for (int dgb = 0; dgb < 2; ++dgb) {
        const int vrow = dgb * 32 + c32;
        const bf16x8 vf0 = *reinterpret_cast<const bf16x8*>(
            vl + vrow * 128 + (((ksw * 4 + h) ^ (c32 & 7)) << 4));
        const bf16x8 vf1 = *reinterpret_cast<const bf16x8*>(
            vl + vrow * 128 + (((ksw * 4 + 2 + h) ^ (c32 & 7)) << 4));
        if (dgb == 0) {
          o0 = __builtin_amdgcn_mfma_f32_32x32x16_bf16(pa1, vf0, o0, 0, 0, 0);
          o0 = __builtin_amdgcn_mfma_f32_32x32x16_bf16(pa2, vf1, o0, 0, 0, 0);
        } else {
          o1 = __builtin_amdgcn_mfma_f32_32x32x16_bf16(pa1, vf0, o1, 0, 0, 0);
          o1 = __builtin_amdgcn_mfma_f32_32x32x16_bf16(pa2, vf1, o1, 0, 0, 0);
        }
      }
    }
    __syncthreads();
  }

  // ---- combine: odd-parity waves dump partials into the dead staging LDS --
  float* const obuf = reinterpret_cast<float*>(lds);           // 4 x 8 KB
  float* const lbuf = reinterpret_cast<float*>(lds + 32768);   // 4 x 32 f32
  if (wave >= 4) {
    float* const ob = obuf + (wave - 4) * 2048;   // [q 0..31][d 0..63]
#pragma unroll
    for (int r = 0; r < 16; ++r) {
      const int qr = (r & 3) + 8 * (r >> 2) + 4 * h;
      ob[qr * 64 + c32] = o0[r];
      ob[qr * 64 + 32 + c32] = o1[r];
      if (c32 == 0) lbuf[(wave - 4) * 32 + qr] = lac[r];
    }
  }
  __syncthreads();
  if (wave < 4) {
    const float* const ob = obuf + wave * 2048;
    const float* const lb = lbuf + wave * 32;
    const int b = bh / H_, hh = bh - b * H_;
#pragma unroll
    for (int r = 0; r < 16; ++r) {
      const int qr = (r & 3) + 8 * (r >> 2) + 4 * h;
      const float lt = 1.0f / (lac[r] + lb[qr]);
      const float v0 = o0[r] + ob[qr * 64 + c32];
      const float v1 = o1[r] + ob[qr * 64 + 32 + c32];
      const size_t rowoff = ((size_t)(b * T_ + q0w + qr)) * C_ + hh * HD_;
      O[rowoff + c32] = (bf16_t)(v0 * lt);
      O[rowoff + 32 + c32] = (bf16_t)(v1 * lt);
    }
  }
}

// ---------------------------------------------------------------------------
extern "C" void kernel_launch(void* const* d_in, const int* in_sizes, int n_in,
                              void* d_out, int out_size, void* d_ws,
                              size_t ws_size, hipStream_t stream) {
  const float* x  = (const float*)d_in[0];   // [2,4096,768]
  const float* wa = (const float*)d_in[1];   // [2304,768]
  const float* wp = (const float*)d_in[2];   // [768,768]
  float* out = (float*)d_out;                // [2,4096,768] f32

  char* ws = (char*)d_ws;
  size_t off = 0;
  auto alloc = [&](size_t bytes) -> char* {
    char* p = ws + off;
    off += (bytes + 255) & ~(size_t)255;
    return p;
  };
  bf16_t* xb  = (bf16_t*)alloc((size_t)M_ * C_ * 2);
  bf16_t* wab = (bf16_t*)alloc((size_t)NQKV_ * C_ * 2);
  bf16_t* wpb = (bf16_t*)alloc((size_t)C_ * C_ * 2);
  bf16_t* Qb  = (bf16_t*)alloc((size_t)B_ * H_ * T_ * HD_ * 2);
  bf16_t* Kb  = (bf16_t*)alloc((size_t)B_ * H_ * T_ * HD_ * 2);
  bf16_t* Vtb = (bf16_t*)alloc((size_t)B_ * H_ * HD_ * T_ * 2);
  bf16_t* Ob  = (bf16_t*)alloc((size_t)M_ * C_ * 2);
  if (off > ws_size) return;

  cvt_all<<<1024, 256, 0, stream>>>(x, wa, wp, xb, wab, wpb);

  gemm_qkv<<<dim3(NQKV_ / 128, M_ / 128), 256, 0, stream>>>(xb, wab, Qb, Kb, Vtb);
  attn_fwd<<<dim3(B_ * H_, 32), 512, 0, stream>>>(Qb, Kb, Vtb, Ob);
  gemm_proj<<<dim3(C_ / 128, M_ / 128), 256, 0, stream>>>(Ob, wpb, out);
}

// Round 16
// 169.553 us; speedup vs baseline: 1.1572x; 1.0013x over previous
//
#include <hip/hip_runtime.h>
#include <hip/hip_bf16.h>
#include <cstdint>
#include <cstddef>

// Problem constants
constexpr int B_ = 2, T_ = 4096, C_ = 768, H_ = 12, HD_ = 64;
constexpr int M_ = B_ * T_;      // 8192 rows of x
constexpr int NQKV_ = 3 * C_;    // 2304

typedef __bf16 bf16_t;
typedef __bf16 bf16x8 __attribute__((ext_vector_type(8)));
typedef __bf16 bf16x4 __attribute__((ext_vector_type(4)));
typedef __bf16 bf16x2 __attribute__((ext_vector_type(2)));
typedef float  f32x4  __attribute__((ext_vector_type(4)));
typedef float  f32x16 __attribute__((ext_vector_type(16)));
typedef unsigned int u32;
typedef unsigned int u32x4 __attribute__((ext_vector_type(4)));

typedef const __attribute__((address_space(1))) void* gas_t;
typedef __attribute__((address_space(3))) void* las_t;

// Q pre-scale: 1/sqrt(64) * log2(e)  (softmax done in exp2 domain).
// Folded into W_attn's Q rows during conversion.
#define QSCALE 0.1803368801111204f

static __device__ __forceinline__ u32 pkbf16(float a, float b) {
  bf16x2 t;
  t[0] = (bf16_t)a;
  t[1] = (bf16_t)b;
  return __builtin_bit_cast(u32, t);
}

// ---------------------------------------------------------------------------
// Merged f32 -> bf16 conversion for x, w_attn, w_proj in ONE launch.
// w_attn rows [0,768) (the Q rows) are pre-scaled by QSCALE.
// ---------------------------------------------------------------------------
constexpr int N4_X  = M_ * C_ / 4;          // 1572864
constexpr int N4_WA = NQKV_ * C_ / 4;       // 442368
constexpr int N4_WP = C_ * C_ / 4;          // 147456
constexpr int N4_QROWS = C_ * C_ / 4;       // wa's first 768 rows in f4 units

__global__ void cvt_all(const float* __restrict__ x,
                        const float* __restrict__ wa,
                        const float* __restrict__ wp,
                        bf16_t* __restrict__ xb,
                        bf16_t* __restrict__ wab,
                        bf16_t* __restrict__ wpb) {
  int i = blockIdx.x * blockDim.x + threadIdx.x;
  const int st = gridDim.x * blockDim.x;
  const int n4 = N4_X + N4_WA + N4_WP;
  for (; i < n4; i += st) {
    const float* s;
    bf16_t* d;
    int k;
    float sc = 1.0f;
    if (i < N4_X) {
      s = x; d = xb; k = i;
    } else if (i < N4_X + N4_WA) {
      s = wa; d = wab; k = i - N4_X;
      if (k < N4_QROWS) sc = QSCALE;
    } else {
      s = wp; d = wpb; k = i - N4_X - N4_WA;
    }
    const float4 v = reinterpret_cast<const float4*>(s)[k];
    bf16x4 o;
    o[0] = (bf16_t)(v.x * sc); o[1] = (bf16_t)(v.y * sc);
    o[2] = (bf16_t)(v.z * sc); o[3] = (bf16_t)(v.w * sc);
    reinterpret_cast<bf16x4*>(d)[k] = o;
  }
}

// ===========================================================================
// Staged GEMM core (m97 structure): 128x128 tile, BK=32, dbuf LDS 32 KB,
// global_load_lds width=16, pre-swizzled source (chunk ^= row&3).
// ===========================================================================
#define GEMM_CORE(Xb, Wb)                                                     \
  __shared__ __align__(16) char lds[32768];                                   \
  const int tid = threadIdx.x, lane = tid & 63, wave = tid >> 6;              \
  const int r16 = lane & 15, g = lane >> 4;                                   \
  const int wr = wave >> 1, wc = wave & 1;                                    \
  const int m0 = blockIdx.y * 128;                                            \
  const int n0 = blockIdx.x * 128;                                            \
  int prow[2], goff[2];                                                       \
  _Pragma("unroll")                                                           \
  for (int i = 0; i < 2; ++i) {                                               \
    const int p = (wave * 2 + i) * 64 + lane;                                 \
    prow[i] = p >> 2;                                                         \
    goff[i] = ((p & 3) ^ (prow[i] & 3)) * 8;                                  \
  }                                                                           \
  auto stage = [&](int buf, int k0) {                                         \
    char* const base = lds + buf * 16384;                                     \
    _Pragma("unroll")                                                         \
    for (int i = 0; i < 2; ++i) {                                             \
      __builtin_amdgcn_global_load_lds(                                       \
          (gas_t)(Xb + (size_t)prow[i] * C_ + k0 + goff[i]),                  \
          (las_t)(base + (wave * 2 + i) * 1024), 16, 0, 0);                   \
      __builtin_amdgcn_global_load_lds(                                       \
          (gas_t)(Wb + (size_t)prow[i] * C_ + k0 + goff[i]),                  \
          (las_t)(base + 8192 + (wave * 2 + i) * 1024), 16, 0, 0);            \
    }                                                                         \
  };                                                                          \
  f32x4 acc[4][4] = {};                                                       \
  const int kswz = (g ^ (r16 & 3)) * 16;                                      \
  stage(0, 0);                                                                \
  __syncthreads();                                                            \
  constexpr int KT = C_ / 32;                                                 \
  for (int kt = 0; kt < KT; ++kt) {                                           \
    if (kt + 1 < KT) stage((kt + 1) & 1, (kt + 1) * 32);                      \
    const char* Ab = lds + (kt & 1) * 16384;                                  \
    const char* Bb = Ab + 8192;                                               \
    bf16x8 a[4], b[4];                                                        \
    _Pragma("unroll")                                                         \
    for (int i = 0; i < 4; ++i)                                               \
      a[i] = *reinterpret_cast<const bf16x8*>(                                \
          Ab + (wr * 64 + i * 16 + r16) * 64 + kswz);                         \
    _Pragma("unroll")                                                         \
    for (int j = 0; j < 4; ++j)                                               \
      b[j] = *reinterpret_cast<const bf16x8*>(                                \
          Bb + (wc * 64 + j * 16 + r16) * 64 + kswz);                         \
    _Pragma("unroll")                                                         \
    for (int i = 0; i < 4; ++i)                                               \
      _Pragma("unroll")                                                       \
      for (int j = 0; j < 4; ++j)                                             \
        acc[i][j] = __builtin_amdgcn_mfma_f32_16x16x32_bf16(                  \
            a[i], b[j], acc[i][j], 0, 0, 0);                                  \
    __syncthreads();                                                          \
  }

// ---------------------------------------------------------------------------
// QKV projection -> Q,K ([B,H,T,64]) and V transposed ([B,H,64,T]).
// QSCALE is pre-folded into W_attn's Q rows.  V packs 4 consecutive-t
// values into one bf16x4 store.
// ---------------------------------------------------------------------------
__global__ __launch_bounds__(256) void gemm_qkv(
    const bf16_t* __restrict__ X, const bf16_t* __restrict__ W,
    bf16_t* __restrict__ Q, bf16_t* __restrict__ K, bf16_t* __restrict__ Vt) {
  GEMM_CORE(X + (size_t)blockIdx.y * 128 * C_,
            W + (size_t)blockIdx.x * 128 * C_)

#pragma unroll
  for (int j = 0; j < 4; ++j) {
    const int col = n0 + wc * 64 + j * 16 + r16;
    const int which = col / C_;           // 0=Q, 1=K, 2=V (wave-uniform)
    const int c = col - which * C_;
    const int h = c >> 6, d = c & 63;
#pragma unroll
    for (int i = 0; i < 4; ++i) {
      const int row0 = m0 + wr * 64 + i * 16 + g * 4;   // quad-aligned
      const int bb = row0 >> 12, t0 = row0 & (T_ - 1);
      if (which == 2) {
        bf16x4 pv;
#pragma unroll
        for (int r = 0; r < 4; ++r) pv[r] = (bf16_t)acc[i][j][r];
        *reinterpret_cast<bf16x4*>(
            &Vt[(((size_t)(bb * H_ + h)) * HD_ + d) * (size_t)T_ + t0]) = pv;
      } else {
        bf16_t* const dst = (which == 0) ? Q : K;
#pragma unroll
        for (int r = 0; r < 4; ++r)
          dst[(((size_t)(bb * H_ + h)) * T_ + t0 + r) * HD_ + d] =
              (bf16_t)acc[i][j][r];
      }
    }
  }
}

// ---------------------------------------------------------------------------
// Output projection: A[8192][768] * Wp[768][768]^T -> f32 out.
// BALANCED GRID: 128x64 tile -> 12 x 64 = 768 blocks = exactly 3/CU
// (the 128x128 version had 384 blocks = 1.5/CU: half the CUs hosted 2
// blocks, half 1 -> ~25% tail idle).  4 waves = 2M x 2N, wave tile 64x32,
// acc[4][2], 24 KB dbuf LDS, same global_load_lds + pre-swizzle scheme.
// ---------------------------------------------------------------------------
__global__ __launch_bounds__(256) void gemm_proj(
    const bf16_t* __restrict__ A, const bf16_t* __restrict__ W,
    float* __restrict__ Out) {
  __shared__ __align__(16) char lds[24576];
  const int tid = threadIdx.x, lane = tid & 63, wave = tid >> 6;
  const int r16 = lane & 15, g = lane >> 4;
  const int wr = wave >> 1, wc = wave & 1;
  const int m0 = blockIdx.y * 128;
  const int n0 = blockIdx.x * 64;
  const bf16_t* const Ag = A + (size_t)m0 * C_;
  const bf16_t* const Wg = W + (size_t)n0 * C_;

  // A: 128 rows x 4 chunks = 512 chunks (2 insts/wave); B: 64 rows = 256 (1)
  int aprow[2], agoff[2];
#pragma unroll
  for (int i = 0; i < 2; ++i) {
    const int p = (wave * 2 + i) * 64 + lane;
    aprow[i] = p >> 2;
    agoff[i] = ((p & 3) ^ (aprow[i] & 3)) * 8;
  }
  const int pb = wave * 64 + lane;
  const int bprow = pb >> 2;
  const int bgoff = ((pb & 3) ^ (bprow & 3)) * 8;

  auto stage = [&](int buf, int k0) {
    char* const base = lds + buf * 12288;
#pragma unroll
    for (int i = 0; i < 2; ++i)
      __builtin_amdgcn_global_load_lds(
          (gas_t)(Ag + (size_t)aprow[i] * C_ + k0 + agoff[i]),
          (las_t)(base + (wave * 2 + i) * 1024), 16, 0, 0);
    __builtin_amdgcn_global_load_lds(
        (gas_t)(Wg + (size_t)bprow * C_ + k0 + bgoff),
        (las_t)(base + 8192 + wave * 1024), 16, 0, 0);
  };

  f32x4 acc[4][2] = {};
  const int kswz = (g ^ (r16 & 3)) * 16;
  stage(0, 0);
  __syncthreads();
  constexpr int KT = C_ / 32;
  for (int kt = 0; kt < KT; ++kt) {
    if (kt + 1 < KT) stage((kt + 1) & 1, (kt + 1) * 32);
    const char* Ab = lds + (kt & 1) * 12288;
    const char* Bb = Ab + 8192;
    bf16x8 a[4], b[2];
#pragma unroll
    for (int i = 0; i < 4; ++i)
      a[i] = *reinterpret_cast<const bf16x8*>(
          Ab + (wr * 64 + i * 16 + r16) * 64 + kswz);
#pragma unroll
    for (int j = 0; j < 2; ++j)
      b[j] = *reinterpret_cast<const bf16x8*>(
          Bb + (wc * 32 + j * 16 + r16) * 64 + kswz);
#pragma unroll
    for (int i = 0; i < 4; ++i)
#pragma unroll
      for (int j = 0; j < 2; ++j)
        acc[i][j] = __builtin_amdgcn_mfma_f32_16x16x32_bf16(
            a[i], b[j], acc[i][j], 0, 0, 0);
    __syncthreads();
  }

#pragma unroll
  for (int j = 0; j < 2; ++j) {
    const int col = n0 + wc * 32 + j * 16 + r16;
#pragma unroll
    for (int i = 0; i < 4; ++i)
#pragma unroll
      for (int r = 0; r < 4; ++r) {
        const int row = m0 + wr * 64 + i * 16 + g * 4 + r;
        Out[(size_t)row * C_ + col] = acc[i][j][r];
      }
  }
}

// ---------------------------------------------------------------------------
// Causal flash attention v9 (VERBATIM round-9/13/15 99us kernel).
// 512 threads = 8 waves.  Waves 0-3: q-groups 0-3 (32q each, 128q block),
// EVEN 32-key subtiles.  Waves 4-7: same q-groups, ODD subtiles.  Fixed-shift
// softmax => partials combine by plain addition through dead staging LDS.
// Grid: (B*H = 24 fastest -> XCD L2 locality, 32), heavy tiles first.
// ---------------------------------------------------------------------------
__global__ __launch_bounds__(512) void attn_fwd(
    const bf16_t* __restrict__ Q, const bf16_t* __restrict__ K,
    const bf16_t* __restrict__ Vt, bf16_t* __restrict__ O) {
  __shared__ __align__(16) char lds[33280];
  const int tid = threadIdx.x;
  const int lane = tid & 63, wave = tid >> 6;    // wave 0..7
  const int wq = wave & 3;                       // q-group
  const int ksw = wave >> 2;                     // subtile parity
  const int c32 = lane & 31, h = lane >> 5;
  const int bh = blockIdx.x;
  const int y = gridDim.y - 1 - blockIdx.y;      // heavy tiles first
  const int q0w = 128 * y + 32 * wq;

  const bf16_t* Qb = Q + (size_t)bh * T_ * HD_;
  const bf16_t* Kb = K + (size_t)bh * T_ * HD_;
  const bf16_t* Vb = Vt + (size_t)bh * HD_ * T_;

  // Q fragments (B operand): col=query=c32, k = dg*16 + h*8 + j
  bf16x8 qf[4];
#pragma unroll
  for (int dg = 0; dg < 4; ++dg)
    qf[dg] = *reinterpret_cast<const bf16x8*>(
        Qb + (size_t)(q0w + c32) * HD_ + dg * 16 + h * 8);

  // all-ones B fragment for the MFMA row-sum
  bf16x8 ones;
#pragma unroll
  for (int q = 0; q < 8; ++q) ones[q] = (bf16_t)1.0f;

  f32x16 o0 = {}, o1 = {};   // d 0..31 / 32..63 for 16 queries (reg=query)
  f32x16 lac = {};           // row sums, same layout as o

  // staging: 512 threads x 2 x 16B (one K chunk, one V chunk) = 16 KB tile.
  // LDS dest linear (pos = tid*16); source chunk pre-swizzled by row&7.
  const int srow = tid >> 3;
  const int sck = (tid & 7) ^ (srow & 7);

  auto STAGE = [&](int t, int buf) {
    char* const kb = lds + buf * 16384;
    __builtin_amdgcn_global_load_lds(
        (gas_t)(Kb + (size_t)(t * 64 + srow) * HD_ + sck * 8),
        (las_t)(kb + wave * 1024), 16, 0, 0);
    __builtin_amdgcn_global_load_lds(
        (gas_t)(Vb + (size_t)srow * T_ + t * 64 + sck * 8),
        (las_t)(kb + 8192 + wave * 1024), 16, 0, 0);
  };

  const int nt = 2 * y + 2;
  STAGE(0, 0);
  __syncthreads();

  for (int t = 0; t < nt; ++t) {
    if (t + 1 < nt) STAGE(t + 1, (t + 1) & 1);
    const char* kl = lds + (t & 1) * 16384;
    const char* vl = kl + 8192;
    const int kb0 = t * 64 + ksw * 32;
    if (kb0 < q0w + 32) {
      // ---- S^T = K Q^T over 32 keys (lane owns query c32) ----
      f32x16 s = {};
#pragma unroll
      for (int dg = 0; dg < 4; ++dg) {
        const bf16x8 kf = *reinterpret_cast<const bf16x8*>(
            kl + (ksw * 32 + c32) * 128 + (((dg * 2 + h) ^ (c32 & 7)) << 4));
        s = __builtin_amdgcn_mfma_f32_32x32x16_bf16(kf, qf[dg], s, 0, 0, 0);
      }
      // ---- causal mask (diagonal-crossing subtiles only) ----
      if (kb0 + 31 > q0w) {
        const int qabs = q0w + c32;
        const int kbh = kb0 + 4 * h;
#pragma unroll
        for (int r = 0; r < 16; ++r) {
          if (kbh + (r & 3) + 8 * (r >> 2) > qabs) s[r] = -130.f;
        }
      }
      // ---- P = exp2(s), fixed shift ----
#pragma unroll
      for (int r = 0; r < 16; ++r) s[r] = exp2f(s[r]);
      // ---- P -> PV A-fragments, fully in-register ----
      u32 X0 = pkbf16(s[0], s[1]),  X1 = pkbf16(s[2], s[3]);
      u32 X2 = pkbf16(s[4], s[5]),  X3 = pkbf16(s[6], s[7]);
      u32 X4 = pkbf16(s[8], s[9]),  X5 = pkbf16(s[10], s[11]);
      u32 X6 = pkbf16(s[12], s[13]), X7 = pkbf16(s[14], s[15]);
      const auto a0 = __builtin_amdgcn_permlane32_swap(X0, X2, false, false);
      const auto a1 = __builtin_amdgcn_permlane32_swap(X1, X3, false, false);
      const auto a2 = __builtin_amdgcn_permlane32_swap(X4, X6, false, false);
      const auto a3 = __builtin_amdgcn_permlane32_swap(X5, X7, false, false);
      const u32x4 w1 = {(u32)a0[0], (u32)a1[0], (u32)a0[1], (u32)a1[1]};
      const u32x4 w2 = {(u32)a2[0], (u32)a3[0], (u32)a2[1], (u32)a3[1]};
      const bf16x8 pa1 = __builtin_bit_cast(bf16x8, w1);  // keys +0..15
      const bf16x8 pa2 = __builtin_bit_cast(bf16x8, w2);  // keys +16..31
      // ---- l += P . 1  (row sums via MFMA; lands in o's layout) ----
      lac = __builtin_amdgcn_mfma_f32_32x32x16_bf16(pa1, ones, lac, 0, 0, 0);
      lac = __builtin_amdgcn_mfma_f32_32x32x16_bf16(pa2, ones, lac, 0, 0, 0);
      // ---- O += P V  (V^T tile rows = d, contiguous keys) ----
#pragma unroll
      for (int dgb = 0; dgb < 2; ++dgb) {
        const int vrow = dgb * 32 + c32;
        const bf16x8 vf0 = *reinterpret_cast<const bf16x8*>(
            vl + vrow * 128 + (((ksw * 4 + h) ^ (c32 & 7)) << 4));
        const bf16x8 vf1 = *reinterpret_cast<const bf16x8*>(
            vl + vrow * 128 + (((ksw * 4 + 2 + h) ^ (c32 & 7)) << 4));
        if (dgb == 0) {
          o0 = __builtin_amdgcn_mfma_f32_32x32x16_bf16(pa1, vf0, o0, 0, 0, 0);
          o0 = __builtin_amdgcn_mfma_f32_32x32x16_bf16(pa2, vf1, o0, 0, 0, 0);
        } else {
          o1 = __builtin_amdgcn_mfma_f32_32x32x16_bf16(pa1, vf0, o1, 0, 0, 0);
          o1 = __builtin_amdgcn_mfma_f32_32x32x16_bf16(pa2, vf1, o1, 0, 0, 0);
        }
      }
    }
    __syncthreads();
  }

  // ---- combine: odd-parity waves dump partials into the dead staging LDS --
  float* const obuf = reinterpret_cast<float*>(lds);           // 4 x 8 KB
  float* const lbuf = reinterpret_cast<float*>(lds + 32768);   // 4 x 32 f32
  if (wave >= 4) {
    float* const ob = obuf + (wave - 4) * 2048;   // [q 0..31][d 0..63]
#pragma unroll
    for (int r = 0; r < 16; ++r) {
      const int qr = (r & 3) + 8 * (r >> 2) + 4 * h;
      ob[qr * 64 + c32] = o0[r];
      ob[qr * 64 + 32 + c32] = o1[r];
      if (c32 == 0) lbuf[(wave - 4) * 32 + qr] = lac[r];
    }
  }
  __syncthreads();
  if (wave < 4) {
    const float* const ob = obuf + wave * 2048;
    const float* const lb = lbuf + wave * 32;
    const int b = bh / H_, hh = bh - b * H_;
#pragma unroll
    for (int r = 0; r < 16; ++r) {
      const int qr = (r & 3) + 8 * (r >> 2) + 4 * h;
      const float lt = 1.0f / (lac[r] + lb[qr]);
      const float v0 = o0[r] + ob[qr * 64 + c32];
      const float v1 = o1[r] + ob[qr * 64 + 32 + c32];
      const size_t rowoff = ((size_t)(b * T_ + q0w + qr)) * C_ + hh * HD_;
      O[rowoff + c32] = (bf16_t)(v0 * lt);
      O[rowoff + 32 + c32] = (bf16_t)(v1 * lt);
    }
  }
}

// ---------------------------------------------------------------------------
extern "C" void kernel_launch(void* const* d_in, const int* in_sizes, int n_in,
                              void* d_out, int out_size, void* d_ws,
                              size_t ws_size, hipStream_t stream) {
  const float* x  = (const float*)d_in[0];   // [2,4096,768]
  const float* wa = (const float*)d_in[1];   // [2304,768]
  const float* wp = (const float*)d_in[2];   // [768,768]
  float* out = (float*)d_out;                // [2,4096,768] f32

  char* ws = (char*)d_ws;
  size_t off = 0;
  auto alloc = [&](size_t bytes) -> char* {
    char* p = ws + off;
    off += (bytes + 255) & ~(size_t)255;
    return p;
  };
  bf16_t* xb  = (bf16_t*)alloc((size_t)M_ * C_ * 2);
  bf16_t* wab = (bf16_t*)alloc((size_t)NQKV_ * C_ * 2);
  bf16_t* wpb = (bf16_t*)alloc((size_t)C_ * C_ * 2);
  bf16_t* Qb  = (bf16_t*)alloc((size_t)B_ * H_ * T_ * HD_ * 2);
  bf16_t* Kb  = (bf16_t*)alloc((size_t)B_ * H_ * T_ * HD_ * 2);
  bf16_t* Vtb = (bf16_t*)alloc((size_t)B_ * H_ * HD_ * T_ * 2);
  bf16_t* Ob  = (bf16_t*)alloc((size_t)M_ * C_ * 2);
  if (off > ws_size) return;

  cvt_all<<<1024, 256, 0, stream>>>(x, wa, wp, xb, wab, wpb);

  gemm_qkv<<<dim3(NQKV_ / 128, M_ / 128), 256, 0, stream>>>(xb, wab, Qb, Kb, Vtb);
  attn_fwd<<<dim3(B_ * H_, 32), 512, 0, stream>>>(Qb, Kb, Vtb, Ob);
  gemm_proj<<<dim3(C_ / 64, M_ / 128), 256, 0, stream>>>(Ob, wpb, out);
}